// Round 1
// 208.794 us; speedup vs baseline: 1.0427x; 1.0427x over previous
//
#include <hip/hip_runtime.h>
#include <stdint.h>

#define PR1 73856093u
#define PR2 19349663u
#define PR3 83492791u
#define PR4 2654435761u
#define GS  32      // chunks per scan group
#define PPT 4       // points per thread per round in k_scatter
#define BBITS 13    // bucket-id bits for ballot match (NB <= 8192)

// Branch-free uniform-divisor mod (exact for h < 2^32 via double).
__device__ __forceinline__ uint32_t fastmod(uint32_t h, uint32_t d, double inv) {
    uint32_t q = (uint32_t)((double)h * inv);
    int32_t r = (int32_t)(h - q * d);
    if (r >= (int32_t)d) r -= d;
    if (r < 0) r += d;
    return (uint32_t)r;
}

// blockIdx -> chunk swizzle: contiguous chunk runs per XCD so rank-adjacent
// output lines are RMW-merged within one XCD's L2. Any bijection is correct.
__device__ __forceinline__ int chunk_of(int bi, int C) {
    return ((C & 7) == 0) ? ((bi & 7) * (C >> 3) + (bi >> 3)) : bi;
}

// K1: bucket per point (float out), per-chunk histogram (u16) -> ch[c][b].
// Vectorized: each lane owns 4 CONSECUTIVE points -> 3x float4 loads +
// 1x float4 bucket store (no ordering constraint here, unlike k_scatter).
// Requires chunk % 4 == 0 (host rounds up; tail guarded).
__global__ __launch_bounds__(256)
void k_bucket_hist(const float* __restrict__ coords,
                   const int* __restrict__ seps, int B,
                   const int* __restrict__ hash_op_p,
                   int N, int NB, int C, int chunk, double invNB,
                   float* __restrict__ out_bucket,
                   uint16_t* __restrict__ ch) {
    extern __shared__ int hist[];          // NB ints (+1 spare, unused here)
    __shared__ int s_seps[1024];
    const int tid = threadIdx.x;
    for (int i = tid; i < NB; i += blockDim.x) hist[i] = 0;
    const int Bc = B < 1024 ? B : 1024;
    for (int j = tid; j < Bc; j += blockDim.x) s_seps[j] = seps[j];
    __syncthreads();

    const uint32_t hop = (uint32_t)hash_op_p[0];
    const int c = chunk_of(blockIdx.x, C);
    const int start = c * chunk;            // chunk%4==0 -> start%4==0
    const int end   = min(start + chunk, N);
    int bid = 0;                            // running searchsorted-right pointer
    for (int i0 = start + tid * 4; i0 < end; i0 += (int)blockDim.x * 4) {
        const int navail = end - i0;        // >= 1
        float xs[4], ys[4], zs[4];
        if (navail >= 4) {
            const float4* cp = (const float4*)(coords + 3 * (size_t)i0);
            const float4 a = cp[0], b4 = cp[1], c4 = cp[2];
            xs[0] = a.x;  ys[0] = a.y;  zs[0] = a.z;
            xs[1] = a.w;  ys[1] = b4.x; zs[1] = b4.y;
            xs[2] = b4.z; ys[2] = b4.w; zs[2] = c4.x;
            xs[3] = c4.y; ys[3] = c4.z; zs[3] = c4.w;
        } else {
            #pragma unroll
            for (int p = 0; p < 4; p++) {
                const int i = i0 + p;
                if (i < end) {
                    xs[p] = coords[3 * (size_t)i + 0];
                    ys[p] = coords[3 * (size_t)i + 1];
                    zs[p] = coords[3 * (size_t)i + 2];
                } else { xs[p] = ys[p] = zs[p] = 0.f; }
            }
        }
        float bf[4];
        #pragma unroll
        for (int p = 0; p < 4; p++) {
            const int i = i0 + p;
            if (i < end) {
                while (bid < B) {
                    const int sv = (bid < 1024) ? s_seps[bid] : seps[bid];
                    if (sv <= i) bid++; else break;
                }
                const uint32_t vx = (uint32_t)(int32_t)floorf(xs[p]);
                const uint32_t vy = (uint32_t)(int32_t)floorf(ys[p]);
                const uint32_t vz = (uint32_t)(int32_t)floorf(zs[p]);
                uint32_t h = vx * PR1 ^ vy * PR2 ^ vz * PR3 ^ ((uint32_t)bid * PR4);
                h += hop;
                const uint32_t b = fastmod(h, (uint32_t)NB, invNB);
                bf[p] = (float)b;
                atomicAdd(&hist[(int)b], 1);   // no return use -> ds_add (cheap)
            } else bf[p] = 0.f;
        }
        if (navail >= 4) {
            *(float4*)(out_bucket + i0) = make_float4(bf[0], bf[1], bf[2], bf[3]);
        } else {
            for (int p = 0; p < navail; p++) out_bucket[i0 + p] = bf[p];
        }
    }
    __syncthreads();
    uint16_t* dst = ch + (size_t)c * NB;
    for (int i = tid; i < NB; i += blockDim.x) dst[i] = (uint16_t)hist[i];
}

// K2a: per bucket, exclusive scan within each group of GS chunks, stored
// CLAMPED at 512 (u16, in place); exact group totals -> Sg[g][b] (int).
__global__ void k_scan_group(uint16_t* __restrict__ ch, int* __restrict__ Sg,
                             int C, int NB) {
    const int b = blockIdx.x * blockDim.x + threadIdx.x;
    if (b >= NB) return;
    const int g  = blockIdx.y;
    const int c0 = g * GS;
    const int c1 = min(c0 + GS, C);
    int run = 0;
    for (int c = c0; c < c1; c++) {
        const size_t idx = (size_t)c * NB + b;
        const int v = ch[idx];
        ch[idx] = (uint16_t)(run < 512 ? run : 512);
        run += v;
    }
    Sg[(size_t)g * NB + b] = run;
}

// K2b: exclusive scan over group totals (int, exact, in place); total ->
// counts (float); fused gap-fill of unwritten slots [min(count,512),512).
__global__ void k_scan_tops(int* __restrict__ Sg, int G, int NB,
                            float* __restrict__ out_counts,
                            float* __restrict__ out_sc) {
    const int b = blockIdx.x * blockDim.x + threadIdx.x;
    if (b >= NB) return;
    int run = 0;
    for (int g = 0; g < G; g++) {
        const size_t idx = (size_t)g * NB + b;
        const int v = Sg[idx];
        Sg[idx] = run;
        run += v;
    }
    out_counts[b] = (float)run;
    const int c0 = run < 512 ? run : 512;
    float* p = out_sc + ((size_t)b * 512 + c0) * 3;
    for (int j = c0; j < 512; j++) {
        p[0] = 0.f; p[1] = 0.f; p[2] = 0.f;
        p += 3;
    }
}

// K3: stable within-bucket rank (arrival order) + scatter.
// Same-bucket lane groups via BBITS ballot multi-split (13 iters).
// Cross-wave arrival order enforced by an LDS BATON (volatile flag +
// s_sleep poll) instead of a __syncthreads turn loop: __syncthreads forces
// vmcnt(0) drain of the previous round's scattered stores; the baton only
// needs lgkmcnt(0) (LDS atomics), so stores drain asynchronously.
__global__ __launch_bounds__(256, 4)
void k_scatter(const float* __restrict__ coords,
               const float* __restrict__ bucket_f,
               const uint16_t* __restrict__ ch,
               const int* __restrict__ Sg,
               int N, int NB, int C, int chunk,
               float* __restrict__ out_sc) {
    extern __shared__ int hist[];          // NB running counters + 1 baton flag
    volatile int* vturn = hist + NB;
    const int tid = threadIdx.x;
    const int c = chunk_of(blockIdx.x, C);
    const int g = c / GS;
    const uint16_t* r1 = ch + (size_t)c * NB;
    const int*      r2 = Sg + (size_t)g * NB;
    for (int i = tid; i < NB; i += blockDim.x) hist[i] = (int)r1[i] + r2[i];
    if (tid == 0) hist[NB] = 0;
    __syncthreads();

    const int start = c * chunk;
    const int end   = min(start + chunk, N);
    const int len   = end > start ? end - start : 0;
    const int per_round = (int)blockDim.x * PPT;     // 1024
    const int rounds = (len + per_round - 1) / per_round;
    const int lane = tid & 63;
    const int wv   = tid >> 6;
    const int nw   = (int)blockDim.x >> 6;
    const unsigned long long ltmask = ((unsigned long long)1 << lane) - 1;

    for (int rd = 0; rd < rounds; rd++) {
        const int wbase = start + rd * per_round + wv * (64 * PPT);
        int bs[PPT], leader[PPT], cntv[PPT], rnk[PPT];
        float cx[PPT], cy[PPT], cz[PPT];

        #pragma unroll
        for (int s = 0; s < PPT; s++) {
            const int i = wbase + s * 64 + lane;
            const bool v = (i < end);
            bs[s] = v ? (int)bucket_f[i] : NB;     // NB = sentinel, fits BBITS
            cx[s] = v ? coords[3 * (size_t)i + 0] : 0.f;
            cy[s] = v ? coords[3 * (size_t)i + 1] : 0.f;
            cz[s] = v ? coords[3 * (size_t)i + 2] : 0.f;
        }

        // Ballot multi-split: mm = mask of lanes with identical bucket id.
        #pragma unroll
        for (int s = 0; s < PPT; s++) {
            const int b = bs[s];
            unsigned long long mm = ~0ull;
            #pragma unroll
            for (int k = 0; k < BBITS; k++) {
                const unsigned long long blt = __ballot(((b >> k) & 1) != 0);
                mm &= ((b >> k) & 1) ? blt : ~blt;
            }
            leader[s] = (int)__builtin_ctzll(mm);
            cntv[s]   = (int)__builtin_popcountll(mm);
            rnk[s]    = (int)__builtin_popcountll(mm & ltmask);
        }

        // Baton acquire: arrival order = wave 0..nw-1 within round, rounds in
        // order. Poll is wave-uniform (broadcast ds_read), s_sleep backoff.
        const int target = rd * nw + wv;
        while (*vturn < target) __builtin_amdgcn_s_sleep(1);
        __builtin_amdgcn_sched_barrier(0);   // insurance: keep atomics below

        int oldv[PPT];
        #pragma unroll
        for (int s = 0; s < PPT; s++) {
            oldv[s] = 0;
            if (bs[s] < NB && lane == leader[s])
                oldv[s] = atomicAdd(&hist[bs[s]], cntv[s]);
        }
        // Baton release: drain LDS ops only (NOT vmcnt), then pass.
        asm volatile("s_waitcnt lgkmcnt(0)" ::: "memory");
        if (lane == 0) *vturn = target + 1;

        int basev[PPT];
        #pragma unroll
        for (int s = 0; s < PPT; s++)
            basev[s] = __shfl(oldv[s], leader[s], 64);

        #pragma unroll
        for (int s = 0; s < PPT; s++) {
            if (bs[s] < NB) {
                const int r = basev[s] + rnk[s];
                if (r < 512) {
                    float* p = out_sc + ((size_t)bs[s] * 512 + r) * 3;
                    p[0] = cx[s]; p[1] = cy[s]; p[2] = cz[s];
                }
            }
        }
    }
}

extern "C" void kernel_launch(void* const* d_in, const int* in_sizes, int n_in,
                              void* d_out, int out_size, void* d_ws, size_t ws_size,
                              hipStream_t stream) {
    const float* coords  = (const float*)d_in[0];
    const int*   seps    = (const int*)d_in[1];
    const int*   hash_op = (const int*)d_in[2];

    const int N = in_sizes[0] / 3;
    const int B = in_sizes[1];
    const int pad_to = ((N + 511) / 512) * 512;
    const int NB = pad_to / 512;

    float* out        = (float*)d_out;
    float* out_counts = out + (size_t)pad_to * 3;
    float* out_bucket = out_counts + NB;

    // Workspace: ch (u16, C x NB) then Sg (int, G x NB).
    int C = 1024;
    while (C > 8) {
        const int G_ = (C + GS - 1) / GS;
        if ((size_t)C * NB * 2 + (size_t)G_ * NB * 4 <= ws_size) break;
        C -= 8;
    }
    const int G = (C + GS - 1) / GS;
    int chunk = (N + C - 1) / C;
    chunk = (chunk + 3) & ~3;              // k1 float4 path needs chunk%4==0
    uint16_t* ch = (uint16_t*)d_ws;
    int* Sg = (int*)((char*)d_ws + (((size_t)C * NB * 2 + 15) & ~(size_t)15));
    const size_t lds = ((size_t)NB + 1) * sizeof(int);   // +1 = baton flag
    const double invNB = 1.0 / (double)NB;

    k_bucket_hist<<<C, 256, lds, stream>>>(coords, seps, B, hash_op, N, NB, C,
                                           chunk, invNB, out_bucket, ch);
    dim3 g2a((NB + 255) / 256, G);
    k_scan_group<<<g2a, 256, 0, stream>>>(ch, Sg, C, NB);
    k_scan_tops<<<(NB + 255) / 256, 256, 0, stream>>>(Sg, G, NB, out_counts, out);
    k_scatter<<<C, 256, lds, stream>>>(coords, out_bucket, ch, Sg,
                                       N, NB, C, chunk, out);
}

// Round 3
// 199.979 us; speedup vs baseline: 1.0887x; 1.0441x over previous
//
#include <hip/hip_runtime.h>
#include <stdint.h>

#define PR1 73856093u
#define PR2 19349663u
#define PR3 83492791u
#define PR4 2654435761u
#define GS  32      // chunks per scan group
#define PPT 4       // points per thread per round in k_scatter
#define BBITS 13    // bucket-id bits for ballot match (NB <= 8192)
#define SMALLB 16   // seps held in SGPRs when B <= SMALLB

// Branch-free uniform-divisor mod (exact for h < 2^32 via double).
__device__ __forceinline__ uint32_t fastmod(uint32_t h, uint32_t d, double inv) {
    uint32_t q = (uint32_t)((double)h * inv);
    int32_t r = (int32_t)(h - q * d);
    if (r >= (int32_t)d) r -= d;
    if (r < 0) r += d;
    return (uint32_t)r;
}

// blockIdx -> chunk swizzle: contiguous chunk runs per XCD so rank-adjacent
// output lines are RMW-merged within one XCD's L2. Any bijection is correct.
__device__ __forceinline__ int chunk_of(int bi, int C) {
    return ((C & 7) == 0) ? ((bi & 7) * (C >> 3) + (bi >> 3)) : bi;
}

// Voxel hash -> bucket id. MUST be bitwise-identical wherever recomputed.
__device__ __forceinline__ uint32_t bucket_of(float x, float y, float z,
                                              uint32_t bid, uint32_t hop,
                                              uint32_t NBu, double invNB) {
    const uint32_t vx = (uint32_t)(int32_t)floorf(x);
    const uint32_t vy = (uint32_t)(int32_t)floorf(y);
    const uint32_t vz = (uint32_t)(int32_t)floorf(z);
    uint32_t h = vx * PR1 ^ vy * PR2 ^ vz * PR3 ^ (bid * PR4);
    h += hop;
    return fastmod(h, NBu, invNB);
}

// K1: bucket per point (float out), per-chunk histogram (u16) -> ch[c][b].
// float4 loads (lane owns 4 consecutive points). B<=16: seps live in SGPRs,
// batch id = 16 branch-free compares (no loop-carried LDS chain).
__global__ __launch_bounds__(256)
void k_bucket_hist(const float* __restrict__ coords,
                   const int* __restrict__ seps, int B,
                   const int* __restrict__ hash_op_p,
                   int N, int NB, int C, int chunk, double invNB,
                   float* __restrict__ out_bucket,
                   uint16_t* __restrict__ ch) {
    extern __shared__ int hist[];          // NB ints
    __shared__ int s_seps[1024];
    const int tid = threadIdx.x;
    for (int i = tid; i < NB; i += blockDim.x) hist[i] = 0;
    const bool smallB = (B <= SMALLB);
    int sv[SMALLB];
    if (smallB) {
        #pragma unroll
        for (int j = 0; j < SMALLB; j++) sv[j] = (j < B) ? seps[j] : 0x7fffffff;
    } else {
        const int Bc = B < 1024 ? B : 1024;
        for (int j = tid; j < Bc; j += blockDim.x) s_seps[j] = seps[j];
    }
    __syncthreads();

    const uint32_t hop = (uint32_t)hash_op_p[0];
    const uint32_t NBu = (uint32_t)NB;
    const int c = chunk_of(blockIdx.x, C);
    const int start = c * chunk;            // chunk%4==0 -> start%4==0
    const int end   = min(start + chunk, N);
    int bid = 0;                            // fallback running pointer (B>16)
    for (int i0 = start + tid * 4; i0 < end; i0 += (int)blockDim.x * 4) {
        const int navail = end - i0;        // >= 1
        float xs[4], ys[4], zs[4];
        if (navail >= 4) {
            const float4* cp = (const float4*)(coords + 3 * (size_t)i0);
            const float4 a = cp[0], b4 = cp[1], c4 = cp[2];
            xs[0] = a.x;  ys[0] = a.y;  zs[0] = a.z;
            xs[1] = a.w;  ys[1] = b4.x; zs[1] = b4.y;
            xs[2] = b4.z; ys[2] = b4.w; zs[2] = c4.x;
            xs[3] = c4.y; ys[3] = c4.z; zs[3] = c4.w;
        } else {
            #pragma unroll
            for (int p = 0; p < 4; p++) {
                const int i = i0 + p;
                if (i < end) {
                    xs[p] = coords[3 * (size_t)i + 0];
                    ys[p] = coords[3 * (size_t)i + 1];
                    zs[p] = coords[3 * (size_t)i + 2];
                } else { xs[p] = ys[p] = zs[p] = 0.f; }
            }
        }
        float bf[4];
        #pragma unroll
        for (int p = 0; p < 4; p++) {
            const int i = i0 + p;
            if (i < end) {
                int mybid;
                if (smallB) {
                    mybid = 0;
                    #pragma unroll
                    for (int j = 0; j < SMALLB; j++) mybid += (sv[j] <= i) ? 1 : 0;
                } else {
                    while (bid < B) {
                        const int svv = (bid < 1024) ? s_seps[bid] : seps[bid];
                        if (svv <= i) bid++; else break;
                    }
                    mybid = bid;
                }
                const uint32_t b = bucket_of(xs[p], ys[p], zs[p],
                                             (uint32_t)mybid, hop, NBu, invNB);
                bf[p] = (float)b;
                atomicAdd(&hist[(int)b], 1);   // no return use -> ds_add (cheap)
            } else bf[p] = 0.f;
        }
        if (navail >= 4) {
            *(float4*)(out_bucket + i0) = make_float4(bf[0], bf[1], bf[2], bf[3]);
        } else {
            for (int p = 0; p < navail; p++) out_bucket[i0 + p] = bf[p];
        }
    }
    __syncthreads();
    uint16_t* dst = ch + (size_t)c * NB;
    for (int i = tid; i < NB; i += blockDim.x) dst[i] = (uint16_t)hist[i];
}

// K2a: per bucket, exclusive scan within each group of GS chunks, stored
// CLAMPED at 512 (u16, in place); exact group totals -> Sg[g][b] (int).
__global__ void k_scan_group(uint16_t* __restrict__ ch, int* __restrict__ Sg,
                             int C, int NB) {
    const int b = blockIdx.x * blockDim.x + threadIdx.x;
    if (b >= NB) return;
    const int g  = blockIdx.y;
    const int c0 = g * GS;
    const int c1 = min(c0 + GS, C);
    int run = 0;
    for (int c = c0; c < c1; c++) {
        const size_t idx = (size_t)c * NB + b;
        const int v = ch[idx];
        ch[idx] = (uint16_t)(run < 512 ? run : 512);
        run += v;
    }
    Sg[(size_t)g * NB + b] = run;
}

// K2b: exclusive scan over group totals (int, exact, in place); total ->
// counts (float); fused gap-fill of unwritten slots [min(count,512),512).
// Scalar dword stores ONLY (a 12B float3-typed store is UB-prone: HIP rank-3
// vectors may be 16B/16-aligned -> OOB/misaligned wide store; crash suspect).
__global__ void k_scan_tops(int* __restrict__ Sg, int G, int NB,
                            float* __restrict__ out_counts,
                            float* __restrict__ out_sc) {
    const int b = blockIdx.x * blockDim.x + threadIdx.x;
    if (b >= NB) return;
    int run = 0;
    for (int g = 0; g < G; g++) {
        const size_t idx = (size_t)g * NB + b;
        const int v = Sg[idx];
        Sg[idx] = run;
        run += v;
    }
    out_counts[b] = (float)run;
    const int c0 = run < 512 ? run : 512;
    float* p = out_sc + ((size_t)b * 512 + c0) * 3;
    for (int j = c0; j < 512; j++) {
        p[0] = 0.f; p[1] = 0.f; p[2] = 0.f;
        p += 3;
    }
}

// K3: stable within-bucket rank (arrival order) + scatter.
// Same-bucket lane groups via BBITS ballot multi-split (13 iters).
// Barrier turn loop for cross-wave arrival order (MEASURED faster than the
// LDS-baton variant: barrier-paced rounds keep same-XCD blocks in lockstep,
// improving L2 write-merge of the scattered 12B stores; baton drift raised
// WRITE_SIZE 152->165MB and dur 78->83us).
// Bucket id RECOMPUTED from coords (bitwise-identical hash) -> no bucket_f
// read (-16MB FETCH). Scalar dword stores (see k_scan_tops comment).
__global__ __launch_bounds__(256, 4)
void k_scatter(const float* __restrict__ coords,
               const int* __restrict__ seps, int B,
               const int* __restrict__ hash_op_p,
               const uint16_t* __restrict__ ch,
               const int* __restrict__ Sg,
               int N, int NB, int C, int chunk, double invNB,
               float* __restrict__ out_sc) {
    extern __shared__ int hist[];          // NB running counters
    const int tid = threadIdx.x;
    const int c = chunk_of(blockIdx.x, C);
    const int g = c / GS;
    const uint16_t* r1 = ch + (size_t)c * NB;
    const int*      r2 = Sg + (size_t)g * NB;
    for (int i = tid; i < NB; i += blockDim.x) hist[i] = (int)r1[i] + r2[i];
    __syncthreads();

    const bool smallB = (B <= SMALLB);
    int sv[SMALLB];
    if (smallB) {
        #pragma unroll
        for (int j = 0; j < SMALLB; j++) sv[j] = (j < B) ? seps[j] : 0x7fffffff;
    }
    const uint32_t hop = (uint32_t)hash_op_p[0];
    const uint32_t NBu = (uint32_t)NB;

    const int start = c * chunk;
    const int end   = min(start + chunk, N);
    const int len   = end > start ? end - start : 0;
    const int per_round = (int)blockDim.x * PPT;     // 1024
    const int rounds = (len + per_round - 1) / per_round;
    const int lane = tid & 63;
    const int wv   = tid >> 6;
    const int nw   = (int)blockDim.x >> 6;
    const unsigned long long ltmask = ((unsigned long long)1 << lane) - 1;
    int fb_bid = 0;                         // fallback running pointer (B>16)

    for (int rd = 0; rd < rounds; rd++) {
        const int wbase = start + rd * per_round + wv * (64 * PPT);
        int bs[PPT], leader[PPT], cntv[PPT], rnk[PPT];
        float cx[PPT], cy[PPT], cz[PPT];

        #pragma unroll
        for (int s = 0; s < PPT; s++) {
            const int i = wbase + s * 64 + lane;
            const bool v = (i < end);
            cx[s] = v ? coords[3 * (size_t)i + 0] : 0.f;
            cy[s] = v ? coords[3 * (size_t)i + 1] : 0.f;
            cz[s] = v ? coords[3 * (size_t)i + 2] : 0.f;
            if (v) {
                int mybid;
                if (smallB) {
                    mybid = 0;
                    #pragma unroll
                    for (int j = 0; j < SMALLB; j++) mybid += (sv[j] <= i) ? 1 : 0;
                } else {
                    while (fb_bid < B) {
                        if (seps[fb_bid] <= i) fb_bid++; else break;
                    }
                    mybid = fb_bid;
                }
                bs[s] = (int)bucket_of(cx[s], cy[s], cz[s],
                                       (uint32_t)mybid, hop, NBu, invNB);
            } else {
                bs[s] = NB;                // sentinel, fits BBITS
            }
        }

        // Ballot multi-split: mm = mask of lanes with identical bucket id.
        #pragma unroll
        for (int s = 0; s < PPT; s++) {
            const int b = bs[s];
            unsigned long long mm = ~0ull;
            #pragma unroll
            for (int k = 0; k < BBITS; k++) {
                const unsigned long long blt = __ballot(((b >> k) & 1) != 0);
                mm &= ((b >> k) & 1) ? blt : ~blt;
            }
            leader[s] = (int)__builtin_ctzll(mm);
            cntv[s]   = (int)__builtin_popcountll(mm);
            rnk[s]    = (int)__builtin_popcountll(mm & ltmask);
        }

        // Wave turn loop: arrival order = wave 0..nw-1, sub-batch 0..PPT-1.
        int basev[PPT];
        for (int w = 0; w < nw; w++) {
            if (wv == w) {
                #pragma unroll
                for (int s = 0; s < PPT; s++) {
                    int old = 0;
                    if (bs[s] < NB && lane == leader[s])
                        old = atomicAdd(&hist[bs[s]], cntv[s]);
                    basev[s] = __shfl(old, leader[s], 64);
                }
            }
            __syncthreads();
        }

        #pragma unroll
        for (int s = 0; s < PPT; s++) {
            if (bs[s] < NB) {
                const int r = basev[s] + rnk[s];
                if (r < 512) {
                    float* p = out_sc + ((size_t)bs[s] * 512 + r) * 3;
                    p[0] = cx[s]; p[1] = cy[s]; p[2] = cz[s];
                }
            }
        }
    }
}

extern "C" void kernel_launch(void* const* d_in, const int* in_sizes, int n_in,
                              void* d_out, int out_size, void* d_ws, size_t ws_size,
                              hipStream_t stream) {
    const float* coords  = (const float*)d_in[0];
    const int*   seps    = (const int*)d_in[1];
    const int*   hash_op = (const int*)d_in[2];

    const int N = in_sizes[0] / 3;
    const int B = in_sizes[1];
    const int pad_to = ((N + 511) / 512) * 512;
    const int NB = pad_to / 512;

    float* out        = (float*)d_out;
    float* out_counts = out + (size_t)pad_to * 3;
    float* out_bucket = out_counts + NB;

    // Workspace: ch (u16, C x NB) then Sg (int, G x NB).
    int C = 1024;
    while (C > 8) {
        const int G_ = (C + GS - 1) / GS;
        if ((size_t)C * NB * 2 + (size_t)G_ * NB * 4 <= ws_size) break;
        C -= 8;
    }
    const int G = (C + GS - 1) / GS;
    int chunk = (N + C - 1) / C;
    chunk = (chunk + 3) & ~3;              // k1 float4 path needs chunk%4==0
    uint16_t* ch = (uint16_t*)d_ws;
    int* Sg = (int*)((char*)d_ws + (((size_t)C * NB * 2 + 15) & ~(size_t)15));
    const size_t lds = (size_t)NB * sizeof(int);
    const double invNB = 1.0 / (double)NB;

    k_bucket_hist<<<C, 256, lds, stream>>>(coords, seps, B, hash_op, N, NB, C,
                                           chunk, invNB, out_bucket, ch);
    dim3 g2a((NB + 255) / 256, G);
    k_scan_group<<<g2a, 256, 0, stream>>>(ch, Sg, C, NB);
    k_scan_tops<<<(NB + 255) / 256, 256, 0, stream>>>(Sg, G, NB, out_counts, out);
    k_scatter<<<C, 256, lds, stream>>>(coords, seps, B, hash_op, ch, Sg,
                                       N, NB, C, chunk, invNB, out);
}

// Round 4
// 199.078 us; speedup vs baseline: 1.0936x; 1.0045x over previous
//
#include <hip/hip_runtime.h>
#include <stdint.h>

#define PR1 73856093u
#define PR2 19349663u
#define PR3 83492791u
#define PR4 2654435761u
#define GS  32      // chunks per scan group
#define PPT 8       // points per thread per round in k_scatter (8: halves
                    // barrier count and doubles per-window write density ->
                    // better L2 merge of 12B scattered stores)
#define BBITS 13    // bucket-id bits for ballot match (NB <= 8192)
#define SMALLB 16   // seps held in SGPRs when B <= SMALLB

// Branch-free uniform-divisor mod (exact for h < 2^32 via double).
__device__ __forceinline__ uint32_t fastmod(uint32_t h, uint32_t d, double inv) {
    uint32_t q = (uint32_t)((double)h * inv);
    int32_t r = (int32_t)(h - q * d);
    if (r >= (int32_t)d) r -= d;
    if (r < 0) r += d;
    return (uint32_t)r;
}

// blockIdx -> chunk swizzle: contiguous chunk runs per XCD so rank-adjacent
// output lines are RMW-merged within one XCD's L2. Any bijection is correct.
__device__ __forceinline__ int chunk_of(int bi, int C) {
    return ((C & 7) == 0) ? ((bi & 7) * (C >> 3) + (bi >> 3)) : bi;
}

// Voxel hash -> bucket id. MUST be bitwise-identical wherever recomputed.
__device__ __forceinline__ uint32_t bucket_of(float x, float y, float z,
                                              uint32_t bid, uint32_t hop,
                                              uint32_t NBu, double invNB) {
    const uint32_t vx = (uint32_t)(int32_t)floorf(x);
    const uint32_t vy = (uint32_t)(int32_t)floorf(y);
    const uint32_t vz = (uint32_t)(int32_t)floorf(z);
    uint32_t h = vx * PR1 ^ vy * PR2 ^ vz * PR3 ^ (bid * PR4);
    h += hop;
    return fastmod(h, NBu, invNB);
}

// K1: bucket per point (float out), per-chunk histogram (u16) -> ch[c][b].
// float4 loads (lane owns 4 consecutive points). B<=16: seps live in SGPRs.
__global__ __launch_bounds__(256)
void k_bucket_hist(const float* __restrict__ coords,
                   const int* __restrict__ seps, int B,
                   const int* __restrict__ hash_op_p,
                   int N, int NB, int C, int chunk, double invNB,
                   float* __restrict__ out_bucket,
                   uint16_t* __restrict__ ch) {
    extern __shared__ int hist[];          // NB ints
    __shared__ int s_seps[1024];
    const int tid = threadIdx.x;
    for (int i = tid; i < NB; i += blockDim.x) hist[i] = 0;
    const bool smallB = (B <= SMALLB);
    int sv[SMALLB];
    if (smallB) {
        #pragma unroll
        for (int j = 0; j < SMALLB; j++) sv[j] = (j < B) ? seps[j] : 0x7fffffff;
    } else {
        const int Bc = B < 1024 ? B : 1024;
        for (int j = tid; j < Bc; j += blockDim.x) s_seps[j] = seps[j];
    }
    __syncthreads();

    const uint32_t hop = (uint32_t)hash_op_p[0];
    const uint32_t NBu = (uint32_t)NB;
    const int c = chunk_of(blockIdx.x, C);
    const int start = c * chunk;            // chunk%4==0 -> start%4==0
    const int end   = min(start + chunk, N);
    int bid = 0;                            // fallback running pointer (B>16)
    for (int i0 = start + tid * 4; i0 < end; i0 += (int)blockDim.x * 4) {
        const int navail = end - i0;        // >= 1
        float xs[4], ys[4], zs[4];
        if (navail >= 4) {
            const float4* cp = (const float4*)(coords + 3 * (size_t)i0);
            const float4 a = cp[0], b4 = cp[1], c4 = cp[2];
            xs[0] = a.x;  ys[0] = a.y;  zs[0] = a.z;
            xs[1] = a.w;  ys[1] = b4.x; zs[1] = b4.y;
            xs[2] = b4.z; ys[2] = b4.w; zs[2] = c4.x;
            xs[3] = c4.y; ys[3] = c4.z; zs[3] = c4.w;
        } else {
            #pragma unroll
            for (int p = 0; p < 4; p++) {
                const int i = i0 + p;
                if (i < end) {
                    xs[p] = coords[3 * (size_t)i + 0];
                    ys[p] = coords[3 * (size_t)i + 1];
                    zs[p] = coords[3 * (size_t)i + 2];
                } else { xs[p] = ys[p] = zs[p] = 0.f; }
            }
        }
        float bf[4];
        #pragma unroll
        for (int p = 0; p < 4; p++) {
            const int i = i0 + p;
            if (i < end) {
                int mybid;
                if (smallB) {
                    mybid = 0;
                    #pragma unroll
                    for (int j = 0; j < SMALLB; j++) mybid += (sv[j] <= i) ? 1 : 0;
                } else {
                    while (bid < B) {
                        const int svv = (bid < 1024) ? s_seps[bid] : seps[bid];
                        if (svv <= i) bid++; else break;
                    }
                    mybid = bid;
                }
                const uint32_t b = bucket_of(xs[p], ys[p], zs[p],
                                             (uint32_t)mybid, hop, NBu, invNB);
                bf[p] = (float)b;
                atomicAdd(&hist[(int)b], 1);   // no return use -> ds_add (cheap)
            } else bf[p] = 0.f;
        }
        if (navail >= 4) {
            *(float4*)(out_bucket + i0) = make_float4(bf[0], bf[1], bf[2], bf[3]);
        } else {
            for (int p = 0; p < navail; p++) out_bucket[i0 + p] = bf[p];
        }
    }
    __syncthreads();
    uint16_t* dst = ch + (size_t)c * NB;
    for (int i = tid; i < NB; i += blockDim.x) dst[i] = (uint16_t)hist[i];
}

// K2a: per bucket, exclusive scan within each group of GS chunks, stored
// CLAMPED at 512 (u16, in place); exact group totals -> Sg[g][b] (int).
// 64-thread blocks: same work, 4x more blocks -> better CU spread.
__global__ void k_scan_group(uint16_t* __restrict__ ch, int* __restrict__ Sg,
                             int C, int NB) {
    const int b = blockIdx.x * blockDim.x + threadIdx.x;
    if (b >= NB) return;
    const int g  = blockIdx.y;
    const int c0 = g * GS;
    const int c1 = min(c0 + GS, C);
    int run = 0;
    for (int c = c0; c < c1; c++) {
        const size_t idx = (size_t)c * NB + b;
        const int v = ch[idx];
        ch[idx] = (uint16_t)(run < 512 ? run : 512);
        run += v;
    }
    Sg[(size_t)g * NB + b] = run;
}

// K2b: exclusive scan over group totals (int, exact, in place); total ->
// counts (float); fused gap-fill of unwritten slots [min(count,512),512).
// Scalar dword stores only (12B float3 store is UB-prone: rank-3 vector may
// be 16B/16-aligned -> OOB/misaligned wide store).
__global__ void k_scan_tops(int* __restrict__ Sg, int G, int NB,
                            float* __restrict__ out_counts,
                            float* __restrict__ out_sc) {
    const int b = blockIdx.x * blockDim.x + threadIdx.x;
    if (b >= NB) return;
    int run = 0;
    for (int g = 0; g < G; g++) {
        const size_t idx = (size_t)g * NB + b;
        const int v = Sg[idx];
        Sg[idx] = run;
        run += v;
    }
    out_counts[b] = (float)run;
    const int c0 = run < 512 ? run : 512;
    float* p = out_sc + ((size_t)b * 512 + c0) * 3;
    for (int j = c0; j < 512; j++) {
        p[0] = 0.f; p[1] = 0.f; p[2] = 0.f;
        p += 3;
    }
}

// K3: stable within-bucket rank (arrival order) + scatter.
// Same-bucket lane groups via BBITS ballot multi-split (13 iters).
// Barrier turn loop for cross-wave arrival order (MEASURED faster than the
// LDS-baton variant: lockstep rounds improve L2 write-merge; baton drift
// raised WRITE_SIZE 152->165MB). PPT=8: 2 rounds instead of 4 -> 8 barriers
// per block (was 16) and 2x per-window write density (WRITE-amp theory).
// Bucket id RECOMPUTED from coords (bitwise-identical hash; -8MB FETCH,
// measured 40.6->32.3MB).
__global__ __launch_bounds__(256, 4)
void k_scatter(const float* __restrict__ coords,
               const int* __restrict__ seps, int B,
               const int* __restrict__ hash_op_p,
               const uint16_t* __restrict__ ch,
               const int* __restrict__ Sg,
               int N, int NB, int C, int chunk, double invNB,
               float* __restrict__ out_sc) {
    extern __shared__ int hist[];          // NB running counters
    const int tid = threadIdx.x;
    const int c = chunk_of(blockIdx.x, C);
    const int g = c / GS;
    const uint16_t* r1 = ch + (size_t)c * NB;
    const int*      r2 = Sg + (size_t)g * NB;
    for (int i = tid; i < NB; i += blockDim.x) hist[i] = (int)r1[i] + r2[i];
    __syncthreads();

    const bool smallB = (B <= SMALLB);
    int sv[SMALLB];
    if (smallB) {
        #pragma unroll
        for (int j = 0; j < SMALLB; j++) sv[j] = (j < B) ? seps[j] : 0x7fffffff;
    }
    const uint32_t hop = (uint32_t)hash_op_p[0];
    const uint32_t NBu = (uint32_t)NB;

    const int start = c * chunk;
    const int end   = min(start + chunk, N);
    const int len   = end > start ? end - start : 0;
    const int per_round = (int)blockDim.x * PPT;     // 2048
    const int rounds = (len + per_round - 1) / per_round;
    const int lane = tid & 63;
    const int wv   = tid >> 6;
    const int nw   = (int)blockDim.x >> 6;
    const unsigned long long ltmask = ((unsigned long long)1 << lane) - 1;
    int fb_bid = 0;                         // fallback running pointer (B>16)

    for (int rd = 0; rd < rounds; rd++) {
        const int wbase = start + rd * per_round + wv * (64 * PPT);
        int bs[PPT], leader[PPT], cntv[PPT], rnk[PPT];
        float cx[PPT], cy[PPT], cz[PPT];

        #pragma unroll
        for (int s = 0; s < PPT; s++) {
            const int i = wbase + s * 64 + lane;
            const bool v = (i < end);
            cx[s] = v ? coords[3 * (size_t)i + 0] : 0.f;
            cy[s] = v ? coords[3 * (size_t)i + 1] : 0.f;
            cz[s] = v ? coords[3 * (size_t)i + 2] : 0.f;
            if (v) {
                int mybid;
                if (smallB) {
                    mybid = 0;
                    #pragma unroll
                    for (int j = 0; j < SMALLB; j++) mybid += (sv[j] <= i) ? 1 : 0;
                } else {
                    while (fb_bid < B) {
                        if (seps[fb_bid] <= i) fb_bid++; else break;
                    }
                    mybid = fb_bid;
                }
                bs[s] = (int)bucket_of(cx[s], cy[s], cz[s],
                                       (uint32_t)mybid, hop, NBu, invNB);
            } else {
                bs[s] = NB;                // sentinel, fits BBITS
            }
        }

        // Ballot multi-split: mm = mask of lanes with identical bucket id.
        #pragma unroll
        for (int s = 0; s < PPT; s++) {
            const int b = bs[s];
            unsigned long long mm = ~0ull;
            #pragma unroll
            for (int k = 0; k < BBITS; k++) {
                const unsigned long long blt = __ballot(((b >> k) & 1) != 0);
                mm &= ((b >> k) & 1) ? blt : ~blt;
            }
            leader[s] = (int)__builtin_ctzll(mm);
            cntv[s]   = (int)__builtin_popcountll(mm);
            rnk[s]    = (int)__builtin_popcountll(mm & ltmask);
        }

        // Wave turn loop: arrival order = (round, wave, sub-batch, lane) =
        // ascending point index = reference arrival order.
        int basev[PPT];
        for (int w = 0; w < nw; w++) {
            if (wv == w) {
                #pragma unroll
                for (int s = 0; s < PPT; s++) {
                    int old = 0;
                    if (bs[s] < NB && lane == leader[s])
                        old = atomicAdd(&hist[bs[s]], cntv[s]);
                    basev[s] = __shfl(old, leader[s], 64);
                }
            }
            __syncthreads();
        }

        #pragma unroll
        for (int s = 0; s < PPT; s++) {
            if (bs[s] < NB) {
                const int r = basev[s] + rnk[s];
                if (r < 512) {
                    float* p = out_sc + ((size_t)bs[s] * 512 + r) * 3;
                    p[0] = cx[s]; p[1] = cy[s]; p[2] = cz[s];
                }
            }
        }
    }
}

extern "C" void kernel_launch(void* const* d_in, const int* in_sizes, int n_in,
                              void* d_out, int out_size, void* d_ws, size_t ws_size,
                              hipStream_t stream) {
    const float* coords  = (const float*)d_in[0];
    const int*   seps    = (const int*)d_in[1];
    const int*   hash_op = (const int*)d_in[2];

    const int N = in_sizes[0] / 3;
    const int B = in_sizes[1];
    const int pad_to = ((N + 511) / 512) * 512;
    const int NB = pad_to / 512;

    float* out        = (float*)d_out;
    float* out_counts = out + (size_t)pad_to * 3;
    float* out_bucket = out_counts + NB;

    // Workspace: ch (u16, C x NB) then Sg (int, G x NB).
    int C = 1024;
    while (C > 8) {
        const int G_ = (C + GS - 1) / GS;
        if ((size_t)C * NB * 2 + (size_t)G_ * NB * 4 <= ws_size) break;
        C -= 8;
    }
    const int G = (C + GS - 1) / GS;
    int chunk = (N + C - 1) / C;
    chunk = (chunk + 3) & ~3;              // k1 float4 path needs chunk%4==0
    uint16_t* ch = (uint16_t*)d_ws;
    int* Sg = (int*)((char*)d_ws + (((size_t)C * NB * 2 + 15) & ~(size_t)15));
    const size_t lds = (size_t)NB * sizeof(int);
    const double invNB = 1.0 / (double)NB;

    k_bucket_hist<<<C, 256, lds, stream>>>(coords, seps, B, hash_op, N, NB, C,
                                           chunk, invNB, out_bucket, ch);
    dim3 g2a((NB + 63) / 64, G);
    k_scan_group<<<g2a, 64, 0, stream>>>(ch, Sg, C, NB);
    k_scan_tops<<<(NB + 63) / 64, 64, 0, stream>>>(Sg, G, NB, out_counts, out);
    k_scatter<<<C, 256, lds, stream>>>(coords, seps, B, hash_op, ch, Sg,
                                       N, NB, C, chunk, invNB, out);
}